// Round 7
// baseline (50.378 us; speedup 1.0000x reference)
//
#include <hip/hip_runtime.h>

// B=524288 independent attentions over [S=10, D=6], single fused kernel.
// out[b,q] = sum_k softmax_k(score[q,k]) * vsum[k]
// score[q,k] = t_q . x_k + a_k  (q-constant terms cancel in softmax).
// Constants (computed per-block from weights, overlapped with async staging):
//   G'[d][dp] = log2e * sum_e Wq[e][d] Wk[e][dp]
//   w'[dp]    = log2e * sum_e bq[e]  Wk[e][dp]
//   wvs[d]    = sum_e Wv[e][d],  bvs = sum_e bv[e]
// R6 lesson: 4 structures all hit ~43us; shared costs were the serialized
// 1-block precompute launch and <=5 blocks/CU of memory concurrency. R7 fuses
// the precompute (redundant per block, hidden under staging latency) and halves
// the block footprint (15KB LDS -> up to 10 blocks/CU).

#define NB 524288
#define S 10
#define D 6
#define TPB 128
#define EPB 64                   // elements per block (2 threads per element)
#define XFL (S * D)              // 60 floats per element
#define LDS_FLOATS (EPB * XFL)   // 3840 floats = 15360 B = 15 chunks of 1 KB

__device__ __forceinline__ float pin(float v) {
    return __int_as_float(__builtin_amdgcn_readfirstlane(__float_as_int(v)));
}

__global__ __launch_bounds__(TPB, 4) void attn_fused(const float* __restrict__ x,
                                                     const float* __restrict__ Wk,
                                                     const float* __restrict__ Wq,
                                                     const float* __restrict__ bq,
                                                     const float* __restrict__ Wv,
                                                     const float* __restrict__ bv,
                                                     float* __restrict__ out) {
    __shared__ float xs[LDS_FLOATS];
    const int t = threadIdx.x;
    const int wave = t >> 6;
    const int lane = t & 63;
    const int blk = blockIdx.x;

    // 1) Kick off async coalesced global->LDS staging immediately:
    //    15 chunks of 1 KB (64 lanes x 16 B), 2 waves share them.
    const float* gbase = x + (size_t)blk * LDS_FLOATS;
    #pragma unroll
    for (int i = 0; i < 8; ++i) {
        int c = wave + 2 * i;               // wave-uniform chunk id
        if (c < 15) {
            __builtin_amdgcn_global_load_lds(
                (const __attribute__((address_space(1))) void*)(gbase + c * 256 + lane * 4),
                (__attribute__((address_space(3))) void*)(&xs[c * 256 + lane * 4]),
                16, 0, 0);
        }
    }

    // 2) Compute the 49 constants from the weights while the loads fly.
    //    Weight addresses are wave-uniform (L2-resident, ~600 B total).
    //    All indices compile-time (rule #20); results pinned to SGPRs.
    const float LOG2E = 1.44269504088896340736f;
    float G[36], w[6], wvs[6];
    {
        float wq[36], wk[36];
        #pragma unroll
        for (int i = 0; i < 36; ++i) wq[i] = Wq[i];
        #pragma unroll
        for (int i = 0; i < 36; ++i) wk[i] = Wk[i];
        #pragma unroll
        for (int d = 0; d < 6; ++d)
            #pragma unroll
            for (int dp = 0; dp < 6; ++dp) {
                float g = 0.f;
                #pragma unroll
                for (int e = 0; e < 6; ++e) g += wq[e * 6 + d] * wk[e * 6 + dp];
                G[d * 6 + dp] = pin(g * LOG2E);
            }
        #pragma unroll
        for (int dp = 0; dp < 6; ++dp) {
            float s = 0.f;
            #pragma unroll
            for (int e = 0; e < 6; ++e) s += bq[e] * wk[e * 6 + dp];
            w[dp] = pin(s * LOG2E);
        }
        #pragma unroll
        for (int d = 0; d < 6; ++d) {
            float s = 0.f;
            #pragma unroll
            for (int e = 0; e < 6; ++e) s += Wv[e * 6 + d];
            wvs[d] = pin(s);
        }
    }
    float bvs = 0.f;
    #pragma unroll
    for (int e = 0; e < 6; ++e) bvs += bv[e];
    bvs = pin(bvs);

    __syncthreads();   // staging complete (barrier drains vmcnt)

    const int e = t >> 1;       // local element (pair-lanes share rows -> broadcast)
    const float* xe = &xs[e * XFL];

    // Bulk LDS->reg: 15 x ds_read_b128 (base e*240 B, 16B-aligned).
    float xv[XFL];
    const float4* xr = (const float4*)xe;
    #pragma unroll
    for (int i = 0; i < 15; ++i) {
        float4 v = xr[i];
        xv[4 * i + 0] = v.x;
        xv[4 * i + 1] = v.y;
        xv[4 * i + 2] = v.z;
        xv[4 * i + 3] = v.w;
    }

    // t_q for this thread's 5 queries; query rows depend on runtime h=t&1 ->
    // read through LDS (dynamic base + constant offsets), not xv (rule #20).
    const float* xq0 = xe + (t & 1) * (5 * D);
    float tq[5][6];
    #pragma unroll
    for (int j = 0; j < 5; ++j) {
        float xq[6];
        #pragma unroll
        for (int d = 0; d < 6; ++d) xq[d] = xq0[j * 6 + d];
        #pragma unroll
        for (int dp = 0; dp < 6; ++dp) {
            float s = 0.f;
            #pragma unroll
            for (int d = 0; d < 6; ++d) s += xq[d] * G[d * 6 + dp];
            tq[j][dp] = s;
        }
    }

    // Pure register math: scores + softmax + weighted vsum.
    float num[5] = {0.f, 0.f, 0.f, 0.f, 0.f};
    float den[5] = {0.f, 0.f, 0.f, 0.f, 0.f};
    #pragma unroll
    for (int k = 0; k < S; ++k) {
        float a = 0.f, vk = bvs;
        #pragma unroll
        for (int d = 0; d < 6; ++d) {
            a += w[d] * xv[k * 6 + d];
            vk += wvs[d] * xv[k * 6 + d];
        }
        #pragma unroll
        for (int j = 0; j < 5; ++j) {
            float s = a;
            #pragma unroll
            for (int d = 0; d < 6; ++d) s += tq[j][d] * xv[k * 6 + d];
            float ex = __builtin_amdgcn_exp2f(s);   // scores pre-scaled by log2e
            den[j] += ex;
            num[j] += ex * vk;
        }
    }

    // Thread's 5 outputs contiguous: out flat idx = blk*640 + t*5 + j.
    float* op = out + (size_t)blk * (EPB * S) + t * 5;
    #pragma unroll
    for (int j = 0; j < 5; ++j) op[j] = num[j] * __builtin_amdgcn_rcpf(den[j]);
}

extern "C" void kernel_launch(void* const* d_in, const int* in_sizes, int n_in,
                              void* d_out, int out_size, void* d_ws, size_t ws_size,
                              hipStream_t stream) {
    const float* x  = (const float*)d_in[0];
    const float* Wk = (const float*)d_in[1];
    // d_in[2] = bk: unused (cancels inside softmax)
    const float* Wq = (const float*)d_in[3];
    const float* bq = (const float*)d_in[4];
    const float* Wv = (const float*)d_in[5];
    const float* bv = (const float*)d_in[6];
    float* out = (float*)d_out;

    attn_fused<<<NB / EPB, TPB, 0, stream>>>(x, Wk, Wq, bq, Wv, bv, out);
}